// Round 8
// baseline (142.353 us; speedup 1.0000x reference)
//
#include <hip/hip_runtime.h>
#include <cstdint>
#include <cstddef>

#define T_SEQ 2048
#define D_EMB 1024
#define H_HEADS 16
#define MROWS 4096
// scale * log2(e): softmax computed in exp2 domain; folded into q projection
#define SC2 (0.03125f * 1.44269504f)
#define MASKNEG (-1e30f)

typedef __attribute__((ext_vector_type(8))) short bf16x8;
typedef __attribute__((ext_vector_type(4))) float f32x4;
typedef __attribute__((ext_vector_type(16))) float f32x16;
typedef __attribute__((ext_vector_type(4))) unsigned short us4;

__device__ __forceinline__ unsigned short f2bf(float f) {
  union { float f; uint32_t u; } v; v.f = f;
  uint32_t u = v.u;
  return (unsigned short)((u + 0x7FFFu + ((u >> 16) & 1u)) >> 16);
}

__device__ __forceinline__ uint32_t cvtpk(float lo, float hi) {
  uint32_t r;
  asm("v_cvt_pk_bf16_f32 %0, %1, %2" : "=v"(r) : "v"(lo), "v"(hi));
  return r;
}

__device__ __forceinline__ float fexp2(float x) {
  float r;
  asm("v_exp_f32 %0, %1" : "=v"(r) : "v"(x));
  return r;
}

__device__ __forceinline__ void gl16(const void* g, void* l) {
  __builtin_amdgcn_global_load_lds(
      (const __attribute__((address_space(1))) unsigned int*)g,
      (__attribute__((address_space(3))) unsigned int*)l, 16, 0, 0);
}

// ---------------- fp32 -> bf16 (4 weights only, one dispatch) ----------------
// 4 x 262144 quads = 1048576 -> 4096 blocks.
__global__ __launch_bounds__(256) void cvt_w(
    const float* __restrict__ Wq, const float* __restrict__ Wk,
    const float* __restrict__ Wv, const float* __restrict__ Wo,
    unsigned short* __restrict__ Wqb, unsigned short* __restrict__ Wkb,
    unsigned short* __restrict__ Wvb, unsigned short* __restrict__ Wob) {
  int i = blockIdx.x * 256 + threadIdx.x;
  int s = i >> 18, j = i & 262143;
  const float* src = (s == 0) ? Wq : (s == 1) ? Wk : (s == 2) ? Wv : Wo;
  unsigned short* dst = (s == 0) ? Wqb : (s == 1) ? Wkb : (s == 2) ? Wvb : Wob;
  float4 f = ((const float4*)src)[j];
  us4 o;
  o[0] = f2bf(f.x); o[1] = f2bf(f.y); o[2] = f2bf(f.z); o[3] = f2bf(f.w);
  ((us4*)dst)[j] = o;
}

// ---------------- fused QKV projection GEMM ----------------
// 1D grid 768 blocks, XCD-swizzled. BM=128 BN=128 BK=32, dbuf 2-phase K-loop.
// A staged as fp32 via gl16 into XOR-swizzled LDS (R3-proven), cvtpk at frag read.
// z==0 (q) output pre-scaled by SC2 so attention softmax needs no per-logit scale.
__global__ __launch_bounds__(256) void qkv_gemm(
    const float* __restrict__ Qf, const float* __restrict__ Kf,
    const float* __restrict__ Vf,
    const unsigned short* __restrict__ Wqb, const unsigned short* __restrict__ Wkb,
    const unsigned short* __restrict__ Wvb,
    const float* __restrict__ bq, const float* __restrict__ bk, const float* __restrict__ bv,
    unsigned short* __restrict__ qo, unsigned short* __restrict__ ko,
    unsigned short* __restrict__ vto) {
  const int swz = (blockIdx.x & 7) * 96 + (blockIdx.x >> 3);
  const int bx = swz & 7, by = (swz >> 3) & 31, z = swz >> 8;
  const float* A = (z == 0) ? Qf : (z == 1) ? Kf : Vf;
  const unsigned short* W = (z == 0) ? Wqb : (z == 1) ? Wkb : Wvb;
  const float* bias = (z == 0) ? bq : (z == 1) ? bk : bv;

  __shared__ __align__(16) float Asm[2][128 * 32];          // fp32, swizzled
  __shared__ __align__(16) unsigned short Bsm[2][128 * 32]; // bf16, linear

  const int tid = threadIdx.x;
  const int lane = tid & 63, w = tid >> 6;
  const int fq = lane >> 4, fr = lane & 15;
  const int brow = by * 128, bcol = bx * 128;
  const int wr = (w >> 1) * 64, wc = (w & 1) * 64;

  f32x4 acc[4][4] = {};

#define QKV_STAGE(buf, k0)                                                     \
  {                                                                            \
    _Pragma("unroll") for (int it = 0; it < 4; ++it) {                         \
      int idx = it * 256 + tid;                                                \
      int row = idx >> 3;                                                      \
      int sb = ((idx & 7) * 16) ^ ((row & 7) << 4);                            \
      gl16(&A[(size_t)(brow + row) * D_EMB + (k0) + (sb >> 2)],                \
           (char*)Asm[buf] + idx * 16);                                        \
    }                                                                          \
    _Pragma("unroll") for (int it = 0; it < 2; ++it) {                         \
      int idx = it * 256 + tid;                                                \
      int row = idx >> 2, ce = (idx & 3) * 8;                                  \
      gl16(&W[(size_t)(bcol + row) * D_EMB + (k0) + ce],                       \
           (char*)Bsm[buf] + idx * 16);                                        \
    }                                                                          \
  }

#define QKV_COMPUTE(buf)                                                       \
  {                                                                            \
    bf16x8 af[4], bfr[4];                                                      \
    _Pragma("unroll") for (int i = 0; i < 4; ++i) {                            \
      int row = wr + i * 16 + fr;                                              \
      int x = (row & 7) << 4;                                                  \
      const char* base = (const char*)Asm[buf] + row * 128;                    \
      f32x4 lo = *(const f32x4*)(base + ((fq * 32) ^ x));                      \
      f32x4 hi = *(const f32x4*)(base + ((fq * 32 + 16) ^ x));                 \
      union { bf16x8 v; uint32_t u[4]; } a_;                                   \
      a_.u[0] = cvtpk(lo[0], lo[1]); a_.u[1] = cvtpk(lo[2], lo[3]);            \
      a_.u[2] = cvtpk(hi[0], hi[1]); a_.u[3] = cvtpk(hi[2], hi[3]);            \
      af[i] = a_.v;                                                            \
    }                                                                          \
    _Pragma("unroll") for (int j = 0; j < 4; ++j)                              \
        bfr[j] = *(const bf16x8*)((const char*)Bsm[buf] +                      \
                                  (wc + j * 16 + fr) * 64 + fq * 16);          \
    _Pragma("unroll") for (int i = 0; i < 4; ++i)                              \
        _Pragma("unroll") for (int j = 0; j < 4; ++j)                          \
            acc[i][j] = __builtin_amdgcn_mfma_f32_16x16x32_bf16(               \
                af[i], bfr[j], acc[i][j], 0, 0, 0);                            \
  }

  QKV_STAGE(0, 0);
  __syncthreads();
#pragma unroll 1
  for (int t = 0; t < 32; t += 2) {
    QKV_STAGE(1, (t + 1) * 32);
    QKV_COMPUTE(0);
    __syncthreads();
    if (t + 2 < 32) QKV_STAGE(0, (t + 2) * 32);
    QKV_COMPUTE(1);
    __syncthreads();
  }

  // epilogue
#pragma unroll
  for (int i = 0; i < 4; ++i) {
#pragma unroll
    for (int j = 0; j < 4; ++j) {
      int r0 = brow + wr + i * 16 + fq * 4;
      int cc = bcol + wc + j * 16 + fr;
      float bb = bias[cc];
      if (z < 2) {
        unsigned short* O = (z == 0) ? qo : ko;
        float sc = (z == 0) ? SC2 : 1.0f;
#pragma unroll
        for (int q = 0; q < 4; ++q)
          O[(size_t)(r0 + q) * D_EMB + cc] = f2bf((acc[i][j][q] + bb) * sc);
      } else {
        int hh = cc >> 6, dd = cc & 63;
        int mm = r0 >> 11, tt = r0 & 2047;
        us4 pk;
#pragma unroll
        for (int q = 0; q < 4; ++q) pk[q] = f2bf(acc[i][j][q] + bb);
        *(us4*)&vto[((size_t)((mm * H_HEADS + hh) * 64 + dd)) * T_SEQ + tt] = pk;
      }
    }
  }
}

// ---------------- output projection GEMM ----------------
__global__ __launch_bounds__(256) void out_gemm(const unsigned short* __restrict__ Ab,
                                                const unsigned short* __restrict__ Wb,
                                                const float* __restrict__ bias,
                                                float* __restrict__ Out) {
  const int swz = (blockIdx.x & 7) * 64 + (blockIdx.x >> 3);
  const int bx = swz & 15, by = swz >> 4;

  __shared__ __align__(16) unsigned short Asm[2][128 * 32];
  __shared__ __align__(16) unsigned short Bsm[2][64 * 32];
  const int tid = threadIdx.x;
  const int lane = tid & 63, w = tid >> 6;
  const int fq = lane >> 4, fr = lane & 15;
  const int brow = by * 128, bcol = bx * 64;
  const int wr = w * 32;

  f32x4 acc[2][4] = {};

#define OUT_STAGE(buf, k0)                                                     \
  {                                                                            \
    _Pragma("unroll") for (int it = 0; it < 2; ++it) {                         \
      int idx = it * 256 + tid;                                                \
      int row = idx >> 2, ce = (idx & 3) * 8;                                  \
      gl16(&Ab[(size_t)(brow + row) * D_EMB + (k0) + ce],                      \
           (char*)Asm[buf] + idx * 16);                                        \
    }                                                                          \
    {                                                                          \
      int row = tid >> 2, ce = (tid & 3) * 8;                                  \
      gl16(&Wb[(size_t)(bcol + row) * D_EMB + (k0) + ce],                      \
           (char*)Bsm[buf] + tid * 16);                                        \
    }                                                                          \
  }

#define OUT_COMPUTE(buf)                                                       \
  {                                                                            \
    bf16x8 af[2], bfr[4];                                                      \
    _Pragma("unroll") for (int i = 0; i < 2; ++i)                              \
        af[i] = *(const bf16x8*)((const char*)Asm[buf] +                       \
                                 (wr + i * 16 + fr) * 64 + fq * 16);           \
    _Pragma("unroll") for (int j = 0; j < 4; ++j)                              \
        bfr[j] = *(const bf16x8*)((const char*)Bsm[buf] +                      \
                                  (j * 16 + fr) * 64 + fq * 16);               \
    _Pragma("unroll") for (int i = 0; i < 2; ++i)                              \
        _Pragma("unroll") for (int j = 0; j < 4; ++j)                          \
            acc[i][j] = __builtin_amdgcn_mfma_f32_16x16x32_bf16(               \
                af[i], bfr[j], acc[i][j], 0, 0, 0);                            \
  }

  OUT_STAGE(0, 0);
  __syncthreads();
#pragma unroll 1
  for (int t = 0; t < 32; t += 2) {
    OUT_STAGE(1, (t + 1) * 32);
    OUT_COMPUTE(0);
    __syncthreads();
    if (t + 2 < 32) OUT_STAGE(0, (t + 2) * 32);
    OUT_COMPUTE(1);
    __syncthreads();
  }

#pragma unroll
  for (int i = 0; i < 2; ++i)
#pragma unroll
    for (int j = 0; j < 4; ++j) {
      int r0 = brow + wr + i * 16 + fq * 4;
      int cc = bcol + j * 16 + fr;
      float bb = bias[cc];
#pragma unroll
      for (int q = 0; q < 4; ++q)
        Out[(size_t)(r0 + q) * D_EMB + cc] = acc[i][j][q] + bb;
    }
}

// ---------------- Flash attention (32x32 MFMA, QBLK=32/wave, dbuf K/V) ----------------
// 1D grid 512 blocks XCD-swizzled; block = 4 waves x 32 q-rows = 128 q. KVBLK=128.
// q_b pre-scaled by SC2 (exp2 domain). No-max softmax, vector liv (R7-proven).
// P redistributed in-register via shfl_xor(.,32) + h2-select (replaces Pw LDS).
__global__ __launch_bounds__(256) void attn_fwd(const unsigned short* __restrict__ qb,
                                                const unsigned short* __restrict__ kb,
                                                const unsigned short* __restrict__ vtb,
                                                const int* __restrict__ maskg,
                                                unsigned short* __restrict__ outb) {
  const int swzb = (blockIdx.x & 7) * 64 + (blockIdx.x >> 3);
  const int qt = swzb & 15, h = (swzb >> 4) & 15, mI = swzb >> 8;
  const int tid = threadIdx.x;
  const int lane = tid & 63, w = tid >> 6;
  const int lq = lane & 31, h2 = lane >> 5;
  const int xk = (lq & 7) << 4;
  const int vx = (lq & 7) << 4;

  __shared__ __align__(16) unsigned short Ksm[2][128 * 64];  // [key][d], swizzled
  __shared__ __align__(16) unsigned short Vsm[2][64 * 128];  // [d][key], swizzled
  __shared__ __align__(16) float Msm[2][128];
  __shared__ int moks[16];

  // ---- per-(m,tile) all-ones mask flags (once per block) ----
  if (tid < 16) moks[tid] = 1;
  __syncthreads();
  {
    int bad = 0;
    const int4* mg = (const int4*)&maskg[mI * T_SEQ + tid * 8];
    int4 a = mg[0], b = mg[1];
    bad |= (a.x == 0) | (a.y == 0) | (a.z == 0) | (a.w == 0);
    bad |= (b.x == 0) | (b.y == 0) | (b.z == 0) | (b.w == 0);
    if (bad) moks[tid >> 4] = 0;
  }
  __syncthreads();
  int okbits = 0;
#pragma unroll
  for (int i = 0; i < 16; ++i) okbits |= (moks[i] != 0) << i;

  // ---- Q fragments in registers (B-frag: col=q=lq, k=d) ----
  const int qrow = qt * 128 + w * 32 + lq;
  bf16x8 qf[4];
#pragma unroll
  for (int db = 0; db < 4; ++db)
    qf[db] = *(const bf16x8*)&qb[((size_t)(mI * T_SEQ) + qrow) * D_EMB + h * 64 + db * 16 + h2 * 8];

  f32x16 oacc[2] = {};
  f32x16 liv = {};

  const unsigned short* kpan = kb + (size_t)(mI * T_SEQ) * D_EMB + h * 64;
  const unsigned short* vpan = vtb + (size_t)(mI * H_HEADS + h) * 64 * T_SEQ;

#define ATTN_STAGE(buf, t)                                                     \
  {                                                                            \
    int k0s = (t) * 128;                                                       \
    _Pragma("unroll") for (int it = 0; it < 4; ++it) {                         \
      int idx = it * 256 + tid;                                                \
      int row = idx >> 3;                                                      \
      int sb = ((idx & 7) * 16) ^ ((row & 7) << 4);                            \
      gl16(kpan + (size_t)(k0s + row) * D_EMB + (sb >> 1),                     \
           (char*)Ksm[buf] + idx * 16);                                        \
    }                                                                          \
    _Pragma("unroll") for (int it = 0; it < 4; ++it) {                         \
      int idx = it * 256 + tid;                                                \
      int row = idx >> 4;                                                      \
      int sb = ((idx & 15) * 16) ^ ((row & 7) << 4);                           \
      gl16(vpan + (size_t)row * T_SEQ + k0s + (sb >> 1),                       \
           (char*)Vsm[buf] + idx * 16);                                        \
    }                                                                          \
    if (!((okbits >> (t)) & 1) && tid < 128)                                   \
      Msm[buf][tid] = (maskg[mI * T_SEQ + k0s + tid] == 0) ? MASKNEG : 0.f;    \
  }

#define ATTN_COMPUTE(buf, okv)                                                 \
  _Pragma("unroll 1") for (int kbk = 0; kbk < 4; ++kbk) {                      \
    f32x16 sv = {};                                                            \
    const char* kr = (const char*)Ksm[buf] + (kbk * 32 + lq) * 128;            \
    _Pragma("unroll") for (int db = 0; db < 4; ++db) {                         \
      bf16x8 kf = *(const bf16x8*)(kr + ((db * 32 + h2 * 16) ^ xk));           \
      sv = __builtin_amdgcn_mfma_f32_32x32x16_bf16(kf, qf[db], sv, 0, 0, 0);   \
    }                                                                          \
    if (!(okv)) {                                                              \
      _Pragma("unroll") for (int rg = 0; rg < 4; ++rg) {                       \
        f32x4 mk = *(const f32x4*)&Msm[buf][kbk * 32 + rg * 8 + h2 * 4];       \
        sv[rg * 4 + 0] += mk[0]; sv[rg * 4 + 1] += mk[1];                      \
        sv[rg * 4 + 2] += mk[2]; sv[rg * 4 + 3] += mk[3];                      \
      }                                                                        \
    }                                                                          \
    _Pragma("unroll") for (int r = 0; r < 16; ++r) sv[r] = fexp2(sv[r]);       \
    liv += sv;                                                                 \
    uint32_t w0 = cvtpk(sv[0], sv[1]), w1 = cvtpk(sv[2], sv[3]);               \
    uint32_t w2 = cvtpk(sv[4], sv[5]), w3 = cvtpk(sv[6], sv[7]);               \
    uint32_t w4 = cvtpk(sv[8], sv[9]), w5 = cvtpk(sv[10], sv[11]);             \
    uint32_t w6 = cvtpk(sv[12], sv[13]), w7 = cvtpk(sv[14], sv[15]);           \
    uint32_t x0 = __shfl_xor(w0, 32), x1 = __shfl_xor(w1, 32);                 \
    uint32_t x2 = __shfl_xor(w2, 32), x3 = __shfl_xor(w3, 32);                 \
    uint32_t x4 = __shfl_xor(w4, 32), x5 = __shfl_xor(w5, 32);                 \
    uint32_t x6 = __shfl_xor(w6, 32), x7 = __shfl_xor(w7, 32);                 \
    bf16x8 pf[2];                                                              \
    {                                                                          \
      union { bf16x8 v; uint32_t u[4]; } u_;                                   \
      u_.u[0] = h2 ? x2 : w0; u_.u[1] = h2 ? x3 : w1;                          \
      u_.u[2] = h2 ? w2 : x0; u_.u[3] = h2 ? w3 : x1;                          \
      pf[0] = u_.v;                                                            \
    }                                                                          \
    {                                                                          \
      union { bf16x8 v; uint32_t u[4]; } u_;                                   \
      u_.u[0] = h2 ? x6 : w4; u_.u[1] = h2 ? x7 : w5;                          \
      u_.u[2] = h2 ? w6 : x4; u_.u[3] = h2 ? w7 : x5;                          \
      pf[1] = u_.v;                                                            \
    }                                                                          \
    _Pragma("unroll") for (int vb = 0; vb < 2; ++vb) {                         \
      const char* vbase = (const char*)Vsm[buf] + (vb * 32 + lq) * 256;        \
      _Pragma("unroll") for (int s = 0; s < 2; ++s) {                          \
        bf16x8 vf = *(const bf16x8*)(vbase +                                   \
                        ((kbk * 64 + s * 32 + h2 * 16) ^ vx));                 \
        oacc[vb] = __builtin_amdgcn_mfma_f32_32x32x16_bf16(                    \
            vf, pf[s], oacc[vb], 0, 0, 0);                                     \
      }                                                                        \
    }                                                                          \
  }

  ATTN_STAGE(0, 0);
  __syncthreads();
#pragma unroll 1
  for (int t = 0; t < 16; t += 2) {
    ATTN_STAGE(1, t + 1);
    {
      const int okv = (okbits >> t) & 1;
      ATTN_COMPUTE(0, okv);
    }
    __syncthreads();
    if (t + 2 < 16) ATTN_STAGE(0, t + 2);
    {
      const int okv = (okbits >> (t + 1)) & 1;
      ATTN_COMPUTE(1, okv);
    }
    __syncthreads();
  }

  // ---- epilogue: horizontal li, cross-half add, divide, store bf16 ----
  float li = 0.f;
#pragma unroll
  for (int r = 0; r < 16; ++r) li += liv[r];
  li += __shfl_xor(li, 32);
  float inv = 1.f / li;
  size_t orow = (size_t)(mI * T_SEQ + qrow) * D_EMB + h * 64;
#pragma unroll
  for (int vb = 0; vb < 2; ++vb)
#pragma unroll
    for (int rg = 0; rg < 4; ++rg) {
      uint2 ow;
      ow.x = cvtpk(oacc[vb][rg * 4 + 0] * inv, oacc[vb][rg * 4 + 1] * inv);
      ow.y = cvtpk(oacc[vb][rg * 4 + 2] * inv, oacc[vb][rg * 4 + 3] * inv);
      *(uint2*)&outb[orow + vb * 32 + rg * 8 + h2 * 4] = ow;
    }
}

extern "C" void kernel_launch(void* const* d_in, const int* in_sizes, int n_in,
                              void* d_out, int out_size, void* d_ws, size_t ws_size,
                              hipStream_t stream) {
  const float* Q  = (const float*)d_in[0];
  const float* K  = (const float*)d_in[1];
  const float* V  = (const float*)d_in[2];
  const int* mask = (const int*)d_in[3];
  const float* Wq = (const float*)d_in[4];
  const float* bq = (const float*)d_in[5];
  const float* Wk = (const float*)d_in[6];
  const float* bk = (const float*)d_in[7];
  const float* Wv = (const float*)d_in[8];
  const float* bv = (const float*)d_in[9];
  const float* Wo = (const float*)d_in[10];
  const float* bo = (const float*)d_in[11];

  uint8_t* ws = (uint8_t*)d_ws;
  const size_t MB = 1u << 20;
  unsigned short* Wq_b = (unsigned short*)(ws + 0 * MB);
  unsigned short* Wk_b = (unsigned short*)(ws + 2 * MB);
  unsigned short* Wv_b = (unsigned short*)(ws + 4 * MB);
  unsigned short* Wo_b = (unsigned short*)(ws + 6 * MB);
  unsigned short* q_b  = (unsigned short*)(ws + 8 * MB);
  unsigned short* k_b  = (unsigned short*)(ws + 16 * MB);
  unsigned short* vt_b = (unsigned short*)(ws + 24 * MB);
  unsigned short* cc_b = (unsigned short*)(ws + 32 * MB);

  cvt_w<<<dim3(4096), dim3(256), 0, stream>>>(Wq, Wk, Wv, Wo,
                                              Wq_b, Wk_b, Wv_b, Wo_b);

  qkv_gemm<<<dim3(768), dim3(256), 0, stream>>>(
      Q, K, V, Wq_b, Wk_b, Wv_b, bq, bk, bv, q_b, k_b, vt_b);

  attn_fwd<<<dim3(512), dim3(256), 0, stream>>>(
      q_b, k_b, vt_b, mask, cc_b);

  out_gemm<<<dim3(512), dim3(256), 0, stream>>>(
      cc_b, Wo_b, bo, (float*)d_out);
}

// Round 9
// 140.264 us; speedup vs baseline: 1.0149x; 1.0149x over previous
//
#include <hip/hip_runtime.h>
#include <cstdint>
#include <cstddef>

#define T_SEQ 2048
#define D_EMB 1024
#define H_HEADS 16
#define MROWS 4096
// scale * log2(e): softmax computed in exp2 domain; folded into q projection
#define SC2 (0.03125f * 1.44269504f)
#define MASKNEG (-1e30f)

typedef __attribute__((ext_vector_type(8))) short bf16x8;
typedef __attribute__((ext_vector_type(4))) float f32x4;
typedef __attribute__((ext_vector_type(16))) float f32x16;
typedef __attribute__((ext_vector_type(4))) unsigned short us4;

__device__ __forceinline__ unsigned short f2bf(float f) {
  union { float f; uint32_t u; } v; v.f = f;
  uint32_t u = v.u;
  return (unsigned short)((u + 0x7FFFu + ((u >> 16) & 1u)) >> 16);
}

__device__ __forceinline__ uint32_t cvtpk(float lo, float hi) {
  uint32_t r;
  asm("v_cvt_pk_bf16_f32 %0, %1, %2" : "=v"(r) : "v"(lo), "v"(hi));
  return r;
}

__device__ __forceinline__ float fexp2(float x) {
  float r;
  asm("v_exp_f32 %0, %1" : "=v"(r) : "v"(x));
  return r;
}

__device__ __forceinline__ void gl16(const void* g, void* l) {
  __builtin_amdgcn_global_load_lds(
      (const __attribute__((address_space(1))) unsigned int*)g,
      (__attribute__((address_space(3))) unsigned int*)l, 16, 0, 0);
}

// ---------------- fused fp32 -> bf16 (3 inputs + 4 weights, one dispatch) ----------------
__global__ __launch_bounds__(256) void cvt_all(
    const float* __restrict__ Q, const float* __restrict__ K, const float* __restrict__ V,
    const float* __restrict__ Wq, const float* __restrict__ Wk,
    const float* __restrict__ Wv, const float* __restrict__ Wo,
    unsigned short* __restrict__ Qb, unsigned short* __restrict__ Kb,
    unsigned short* __restrict__ Vb,
    unsigned short* __restrict__ Wqb, unsigned short* __restrict__ Wkb,
    unsigned short* __restrict__ Wvb, unsigned short* __restrict__ Wob) {
  int i = blockIdx.x * 256 + threadIdx.x;
  const float* src;
  unsigned short* dst;
  int j;
  if (i < 3145728) {
    int s = i >> 20;
    j = i & 1048575;
    src = (s == 0) ? Q : (s == 1) ? K : V;
    dst = (s == 0) ? Qb : (s == 1) ? Kb : Vb;
  } else {
    int k = i - 3145728;
    int s = k >> 18;
    j = k & 262143;
    src = (s == 0) ? Wq : (s == 1) ? Wk : (s == 2) ? Wv : Wo;
    dst = (s == 0) ? Wqb : (s == 1) ? Wkb : (s == 2) ? Wvb : Wob;
  }
  float4 f = ((const float4*)src)[j];
  us4 o;
  o[0] = f2bf(f.x); o[1] = f2bf(f.y); o[2] = f2bf(f.z); o[3] = f2bf(f.w);
  ((us4*)dst)[j] = o;
}

// ---------------- fused QKV projection GEMM (R7-proven bf16-A version) ----------------
// 1D grid 768 blocks, XCD-swizzled. BM=128 BN=128 BK=32, dbuf 2-phase K-loop.
// z==0 (q) output pre-scaled by SC2 so attention softmax needs no per-logit scale.
__global__ __launch_bounds__(256) void qkv_gemm(
    const unsigned short* __restrict__ Qb, const unsigned short* __restrict__ Kb,
    const unsigned short* __restrict__ Vb,
    const unsigned short* __restrict__ Wqb, const unsigned short* __restrict__ Wkb,
    const unsigned short* __restrict__ Wvb,
    const float* __restrict__ bq, const float* __restrict__ bk, const float* __restrict__ bv,
    unsigned short* __restrict__ qo, unsigned short* __restrict__ ko,
    unsigned short* __restrict__ vto) {
  const int swz = (blockIdx.x & 7) * 96 + (blockIdx.x >> 3);
  const int bx = swz & 7, by = (swz >> 3) & 31, z = swz >> 8;
  const unsigned short* A = (z == 0) ? Qb : (z == 1) ? Kb : Vb;
  const unsigned short* W = (z == 0) ? Wqb : (z == 1) ? Wkb : Wvb;
  const float* bias = (z == 0) ? bq : (z == 1) ? bk : bv;

  __shared__ __align__(16) unsigned short Asm[2][128 * 32];
  __shared__ __align__(16) unsigned short Bsm[2][128 * 32];

  const int tid = threadIdx.x;
  const int lane = tid & 63, w = tid >> 6;
  const int fq = lane >> 4, fr = lane & 15;
  const int brow = by * 128, bcol = bx * 128;
  const int wr = (w >> 1) * 64, wc = (w & 1) * 64;

  f32x4 acc[4][4] = {};

#define QKV_STAGE(buf, k0)                                                     \
  {                                                                            \
    _Pragma("unroll") for (int it = 0; it < 2; ++it) {                         \
      int idx = it * 256 + tid;                                                \
      int row = idx >> 2, ce = (idx & 3) * 8;                                  \
      gl16(&A[(size_t)(brow + row) * D_EMB + (k0) + ce],                       \
           (char*)Asm[buf] + idx * 16);                                        \
      gl16(&W[(size_t)(bcol + row) * D_EMB + (k0) + ce],                       \
           (char*)Bsm[buf] + idx * 16);                                        \
    }                                                                          \
  }

#define QKV_COMPUTE(buf)                                                       \
  {                                                                            \
    bf16x8 af[4], bfr[4];                                                      \
    _Pragma("unroll") for (int i = 0; i < 4; ++i)                              \
        af[i] = *(const bf16x8*)((const char*)Asm[buf] +                       \
                                 (wr + i * 16 + fr) * 64 + fq * 16);           \
    _Pragma("unroll") for (int j = 0; j < 4; ++j)                              \
        bfr[j] = *(const bf16x8*)((const char*)Bsm[buf] +                      \
                                  (wc + j * 16 + fr) * 64 + fq * 16);          \
    _Pragma("unroll") for (int i = 0; i < 4; ++i)                              \
        _Pragma("unroll") for (int j = 0; j < 4; ++j)                          \
            acc[i][j] = __builtin_amdgcn_mfma_f32_16x16x32_bf16(               \
                af[i], bfr[j], acc[i][j], 0, 0, 0);                            \
  }

  QKV_STAGE(0, 0);
  __syncthreads();
#pragma unroll 1
  for (int t = 0; t < 32; t += 2) {
    QKV_STAGE(1, (t + 1) * 32);
    QKV_COMPUTE(0);
    __syncthreads();
    if (t + 2 < 32) QKV_STAGE(0, (t + 2) * 32);
    QKV_COMPUTE(1);
    __syncthreads();
  }

  // epilogue
#pragma unroll
  for (int i = 0; i < 4; ++i) {
#pragma unroll
    for (int j = 0; j < 4; ++j) {
      int r0 = brow + wr + i * 16 + fq * 4;
      int cc = bcol + wc + j * 16 + fr;
      float bb = bias[cc];
      if (z < 2) {
        unsigned short* O = (z == 0) ? qo : ko;
        float sc = (z == 0) ? SC2 : 1.0f;
#pragma unroll
        for (int q = 0; q < 4; ++q)
          O[(size_t)(r0 + q) * D_EMB + cc] = f2bf((acc[i][j][q] + bb) * sc);
      } else {
        int hh = cc >> 6, dd = cc & 63;
        int mm = r0 >> 11, tt = r0 & 2047;
        us4 pk;
#pragma unroll
        for (int q = 0; q < 4; ++q) pk[q] = f2bf(acc[i][j][q] + bb);
        *(us4*)&vto[((size_t)((mm * H_HEADS + hh) * 64 + dd)) * T_SEQ + tt] = pk;
      }
    }
  }
}

// ---------------- output projection GEMM ----------------
__global__ __launch_bounds__(256) void out_gemm(const unsigned short* __restrict__ Ab,
                                                const unsigned short* __restrict__ Wb,
                                                const float* __restrict__ bias,
                                                float* __restrict__ Out) {
  const int swz = (blockIdx.x & 7) * 64 + (blockIdx.x >> 3);
  const int bx = swz & 15, by = swz >> 4;

  __shared__ __align__(16) unsigned short Asm[2][128 * 32];
  __shared__ __align__(16) unsigned short Bsm[2][64 * 32];
  const int tid = threadIdx.x;
  const int lane = tid & 63, w = tid >> 6;
  const int fq = lane >> 4, fr = lane & 15;
  const int brow = by * 128, bcol = bx * 64;
  const int wr = w * 32;

  f32x4 acc[2][4] = {};

#define OUT_STAGE(buf, k0)                                                     \
  {                                                                            \
    _Pragma("unroll") for (int it = 0; it < 2; ++it) {                         \
      int idx = it * 256 + tid;                                                \
      int row = idx >> 2, ce = (idx & 3) * 8;                                  \
      gl16(&Ab[(size_t)(brow + row) * D_EMB + (k0) + ce],                      \
           (char*)Asm[buf] + idx * 16);                                        \
    }                                                                          \
    {                                                                          \
      int row = tid >> 2, ce = (tid & 3) * 8;                                  \
      gl16(&Wb[(size_t)(bcol + row) * D_EMB + (k0) + ce],                      \
           (char*)Bsm[buf] + tid * 16);                                        \
    }                                                                          \
  }

#define OUT_COMPUTE(buf)                                                       \
  {                                                                            \
    bf16x8 af[2], bfr[4];                                                      \
    _Pragma("unroll") for (int i = 0; i < 2; ++i)                              \
        af[i] = *(const bf16x8*)((const char*)Asm[buf] +                       \
                                 (wr + i * 16 + fr) * 64 + fq * 16);           \
    _Pragma("unroll") for (int j = 0; j < 4; ++j)                              \
        bfr[j] = *(const bf16x8*)((const char*)Bsm[buf] +                      \
                                  (j * 16 + fr) * 64 + fq * 16);               \
    _Pragma("unroll") for (int i = 0; i < 2; ++i)                              \
        _Pragma("unroll") for (int j = 0; j < 4; ++j)                          \
            acc[i][j] = __builtin_amdgcn_mfma_f32_16x16x32_bf16(               \
                af[i], bfr[j], acc[i][j], 0, 0, 0);                            \
  }

  OUT_STAGE(0, 0);
  __syncthreads();
#pragma unroll 1
  for (int t = 0; t < 32; t += 2) {
    OUT_STAGE(1, (t + 1) * 32);
    OUT_COMPUTE(0);
    __syncthreads();
    if (t + 2 < 32) OUT_STAGE(0, (t + 2) * 32);
    OUT_COMPUTE(1);
    __syncthreads();
  }

#pragma unroll
  for (int i = 0; i < 2; ++i)
#pragma unroll
    for (int j = 0; j < 4; ++j) {
      int r0 = brow + wr + i * 16 + fq * 4;
      int cc = bcol + j * 16 + fr;
      float bb = bias[cc];
#pragma unroll
      for (int q = 0; q < 4; ++q)
        Out[(size_t)(r0 + q) * D_EMB + cc] = acc[i][j][q] + bb;
    }
}

// ---------------- Flash attention (32x32 MFMA, QBLK=32/wave, dbuf K/V) ----------------
// 1D grid 512 blocks XCD-swizzled; block = 4 waves x 32 q-rows = 128 q. KVBLK=128.
// q_b pre-scaled by SC2 (exp2 domain). No-max softmax, vector liv (R7-proven).
// P redistributed in-register via shfl_xor(.,32) + h2-select (R8-proven).
__global__ __launch_bounds__(256) void attn_fwd(const unsigned short* __restrict__ qb,
                                                const unsigned short* __restrict__ kb,
                                                const unsigned short* __restrict__ vtb,
                                                const int* __restrict__ maskg,
                                                unsigned short* __restrict__ outb) {
  const int swzb = (blockIdx.x & 7) * 64 + (blockIdx.x >> 3);
  const int qt = swzb & 15, h = (swzb >> 4) & 15, mI = swzb >> 8;
  const int tid = threadIdx.x;
  const int lane = tid & 63, w = tid >> 6;
  const int lq = lane & 31, h2 = lane >> 5;
  const int xk = (lq & 7) << 4;
  const int vx = (lq & 7) << 4;

  __shared__ __align__(16) unsigned short Ksm[2][128 * 64];  // [key][d], swizzled
  __shared__ __align__(16) unsigned short Vsm[2][64 * 128];  // [d][key], swizzled
  __shared__ __align__(16) float Msm[2][128];
  __shared__ int moks[16];

  // ---- per-(m,tile) all-ones mask flags (once per block) ----
  if (tid < 16) moks[tid] = 1;
  __syncthreads();
  {
    int bad = 0;
    const int4* mg = (const int4*)&maskg[mI * T_SEQ + tid * 8];
    int4 a = mg[0], b = mg[1];
    bad |= (a.x == 0) | (a.y == 0) | (a.z == 0) | (a.w == 0);
    bad |= (b.x == 0) | (b.y == 0) | (b.z == 0) | (b.w == 0);
    if (bad) moks[tid >> 4] = 0;
  }
  __syncthreads();
  int okbits = 0;
#pragma unroll
  for (int i = 0; i < 16; ++i) okbits |= (moks[i] != 0) << i;

  // ---- Q fragments in registers (B-frag: col=q=lq, k=d) ----
  const int qrow = qt * 128 + w * 32 + lq;
  bf16x8 qf[4];
#pragma unroll
  for (int db = 0; db < 4; ++db)
    qf[db] = *(const bf16x8*)&qb[((size_t)(mI * T_SEQ) + qrow) * D_EMB + h * 64 + db * 16 + h2 * 8];

  f32x16 oacc[2] = {};
  f32x16 liv = {};

  const unsigned short* kpan = kb + (size_t)(mI * T_SEQ) * D_EMB + h * 64;
  const unsigned short* vpan = vtb + (size_t)(mI * H_HEADS + h) * 64 * T_SEQ;

#define ATTN_STAGE(buf, t)                                                     \
  {                                                                            \
    int k0s = (t) * 128;                                                       \
    _Pragma("unroll") for (int it = 0; it < 4; ++it) {                         \
      int idx = it * 256 + tid;                                                \
      int row = idx >> 3;                                                      \
      int sb = ((idx & 7) * 16) ^ ((row & 7) << 4);                            \
      gl16(kpan + (size_t)(k0s + row) * D_EMB + (sb >> 1),                     \
           (char*)Ksm[buf] + idx * 16);                                        \
    }                                                                          \
    _Pragma("unroll") for (int it = 0; it < 4; ++it) {                         \
      int idx = it * 256 + tid;                                                \
      int row = idx >> 4;                                                      \
      int sb = ((idx & 15) * 16) ^ ((row & 7) << 4);                           \
      gl16(vpan + (size_t)row * T_SEQ + k0s + (sb >> 1),                       \
           (char*)Vsm[buf] + idx * 16);                                        \
    }                                                                          \
    if (!((okbits >> (t)) & 1) && tid < 128)                                   \
      Msm[buf][tid] = (maskg[mI * T_SEQ + k0s + tid] == 0) ? MASKNEG : 0.f;    \
  }

#define ATTN_COMPUTE(buf, okv)                                                 \
  _Pragma("unroll 1") for (int kbk = 0; kbk < 4; ++kbk) {                      \
    f32x16 sv = {};                                                            \
    const char* kr = (const char*)Ksm[buf] + (kbk * 32 + lq) * 128;            \
    _Pragma("unroll") for (int db = 0; db < 4; ++db) {                         \
      bf16x8 kf = *(const bf16x8*)(kr + ((db * 32 + h2 * 16) ^ xk));           \
      sv = __builtin_amdgcn_mfma_f32_32x32x16_bf16(kf, qf[db], sv, 0, 0, 0);   \
    }                                                                          \
    if (!(okv)) {                                                              \
      _Pragma("unroll") for (int rg = 0; rg < 4; ++rg) {                       \
        f32x4 mk = *(const f32x4*)&Msm[buf][kbk * 32 + rg * 8 + h2 * 4];       \
        sv[rg * 4 + 0] += mk[0]; sv[rg * 4 + 1] += mk[1];                      \
        sv[rg * 4 + 2] += mk[2]; sv[rg * 4 + 3] += mk[3];                      \
      }                                                                        \
    }                                                                          \
    _Pragma("unroll") for (int r = 0; r < 16; ++r) sv[r] = fexp2(sv[r]);       \
    liv += sv;                                                                 \
    uint32_t w0 = cvtpk(sv[0], sv[1]), w1 = cvtpk(sv[2], sv[3]);               \
    uint32_t w2 = cvtpk(sv[4], sv[5]), w3 = cvtpk(sv[6], sv[7]);               \
    uint32_t w4 = cvtpk(sv[8], sv[9]), w5 = cvtpk(sv[10], sv[11]);             \
    uint32_t w6 = cvtpk(sv[12], sv[13]), w7 = cvtpk(sv[14], sv[15]);           \
    uint32_t x0 = __shfl_xor(w0, 32), x1 = __shfl_xor(w1, 32);                 \
    uint32_t x2 = __shfl_xor(w2, 32), x3 = __shfl_xor(w3, 32);                 \
    uint32_t x4 = __shfl_xor(w4, 32), x5 = __shfl_xor(w5, 32);                 \
    uint32_t x6 = __shfl_xor(w6, 32), x7 = __shfl_xor(w7, 32);                 \
    bf16x8 pf[2];                                                              \
    {                                                                          \
      union { bf16x8 v; uint32_t u[4]; } u_;                                   \
      u_.u[0] = h2 ? x2 : w0; u_.u[1] = h2 ? x3 : w1;                          \
      u_.u[2] = h2 ? w2 : x0; u_.u[3] = h2 ? w3 : x1;                          \
      pf[0] = u_.v;                                                            \
    }                                                                          \
    {                                                                          \
      union { bf16x8 v; uint32_t u[4]; } u_;                                   \
      u_.u[0] = h2 ? x6 : w4; u_.u[1] = h2 ? x7 : w5;                          \
      u_.u[2] = h2 ? w6 : x4; u_.u[3] = h2 ? w7 : x5;                          \
      pf[1] = u_.v;                                                            \
    }                                                                          \
    _Pragma("unroll") for (int vb = 0; vb < 2; ++vb) {                         \
      const char* vbase = (const char*)Vsm[buf] + (vb * 32 + lq) * 256;        \
      _Pragma("unroll") for (int s = 0; s < 2; ++s) {                          \
        bf16x8 vf = *(const bf16x8*)(vbase +                                   \
                        ((kbk * 64 + s * 32 + h2 * 16) ^ vx));                 \
        oacc[vb] = __builtin_amdgcn_mfma_f32_32x32x16_bf16(                    \
            vf, pf[s], oacc[vb], 0, 0, 0);                                     \
      }                                                                        \
    }                                                                          \
  }

  ATTN_STAGE(0, 0);
  __syncthreads();
#pragma unroll 1
  for (int t = 0; t < 16; t += 2) {
    ATTN_STAGE(1, t + 1);
    {
      const int okv = (okbits >> t) & 1;
      ATTN_COMPUTE(0, okv);
    }
    __syncthreads();
    if (t + 2 < 16) ATTN_STAGE(0, t + 2);
    {
      const int okv = (okbits >> (t + 1)) & 1;
      ATTN_COMPUTE(1, okv);
    }
    __syncthreads();
  }

  // ---- epilogue: horizontal li, cross-half add, divide, store bf16 ----
  float li = 0.f;
#pragma unroll
  for (int r = 0; r < 16; ++r) li += liv[r];
  li += __shfl_xor(li, 32);
  float inv = 1.f / li;
  size_t orow = (size_t)(mI * T_SEQ + qrow) * D_EMB + h * 64;
#pragma unroll
  for (int vb = 0; vb < 2; ++vb)
#pragma unroll
    for (int rg = 0; rg < 4; ++rg) {
      uint2 ow;
      ow.x = cvtpk(oacc[vb][rg * 4 + 0] * inv, oacc[vb][rg * 4 + 1] * inv);
      ow.y = cvtpk(oacc[vb][rg * 4 + 2] * inv, oacc[vb][rg * 4 + 3] * inv);
      *(uint2*)&outb[orow + vb * 32 + rg * 8 + h2 * 4] = ow;
    }
}

extern "C" void kernel_launch(void* const* d_in, const int* in_sizes, int n_in,
                              void* d_out, int out_size, void* d_ws, size_t ws_size,
                              hipStream_t stream) {
  const float* Q  = (const float*)d_in[0];
  const float* K  = (const float*)d_in[1];
  const float* V  = (const float*)d_in[2];
  const int* mask = (const int*)d_in[3];
  const float* Wq = (const float*)d_in[4];
  const float* bq = (const float*)d_in[5];
  const float* Wk = (const float*)d_in[6];
  const float* bk = (const float*)d_in[7];
  const float* Wv = (const float*)d_in[8];
  const float* bv = (const float*)d_in[9];
  const float* Wo = (const float*)d_in[10];
  const float* bo = (const float*)d_in[11];

  uint8_t* ws = (uint8_t*)d_ws;
  const size_t MB = 1u << 20;
  unsigned short* Wq_b = (unsigned short*)(ws + 0 * MB);
  unsigned short* Wk_b = (unsigned short*)(ws + 2 * MB);
  unsigned short* Wv_b = (unsigned short*)(ws + 4 * MB);
  unsigned short* Wo_b = (unsigned short*)(ws + 6 * MB);
  unsigned short* q_b  = (unsigned short*)(ws + 8 * MB);
  unsigned short* k_b  = (unsigned short*)(ws + 16 * MB);
  unsigned short* vt_b = (unsigned short*)(ws + 24 * MB);
  // Q_b/K_b/V_b (bf16 inputs) at 32/40/48 MB; cc_b aliases Q_b (32 MB):
  // Q_b's last read (qkv_gemm) precedes cc_b's first write (attn_fwd).
  unsigned short* Qb   = (unsigned short*)(ws + 32 * MB);
  unsigned short* Kb   = (unsigned short*)(ws + 40 * MB);
  unsigned short* Vb   = (unsigned short*)(ws + 48 * MB);
  unsigned short* cc_b = (unsigned short*)(ws + 32 * MB);

  cvt_all<<<dim3(16384), dim3(256), 0, stream>>>(Q, K, V, Wq, Wk, Wv, Wo,
                                                 Qb, Kb, Vb, Wq_b, Wk_b, Wv_b, Wo_b);

  qkv_gemm<<<dim3(768), dim3(256), 0, stream>>>(
      Qb, Kb, Vb, Wq_b, Wk_b, Wv_b, bq, bk, bv, q_b, k_b, vt_b);

  attn_fwd<<<dim3(512), dim3(256), 0, stream>>>(
      q_b, k_b, vt_b, mask, cc_b);

  out_gemm<<<dim3(512), dim3(256), 0, stream>>>(
      cc_b, Wo_b, bo, (float*)d_out);
}